// Round 3
// baseline (44219.080 us; speedup 1.0000x reference)
//
#include <hip/hip_runtime.h>
#include <math.h>

#define VOCAB  32000
#define EMB    256
#define HID    512
#define MAXLEN 512
#define BATCH  128
#define NCLASS 2

// ---------------------------------------------------------------------------
// Kernel A: embW[v][j] = b_h[j] + sum_e emb[v][e] * W_ih[e][j]
// (unchanged from R0 — ~70 us, not the bottleneck)
// ---------------------------------------------------------------------------
__global__ __launch_bounds__(256, 1) void embw_kernel(
    const float* __restrict__ emb, const float* __restrict__ W_ih,
    const float* __restrict__ b_h, float* __restrict__ embW)
{
    __shared__ __align__(16) float aT[EMB][64];
    __shared__ __align__(16) float wS[32][HID];

    const int t    = threadIdx.x;
    const int row0 = blockIdx.x * 64;

    {
        const int row   = t >> 2;
        const int elane = t & 3;
        for (int i = 0; i < 16; ++i) {
            const int e = elane * 4 + i * 16;
            const float4 v = *reinterpret_cast<const float4*>(
                &emb[(size_t)(row0 + row) * EMB + e]);
            aT[e + 0][row] = v.x;
            aT[e + 1][row] = v.y;
            aT[e + 2][row] = v.z;
            aT[e + 3][row] = v.w;
        }
    }

    const int rg = t >> 5;
    const int cg = t & 31;

    float acc[8][16];
    #pragma unroll
    for (int r = 0; r < 8; ++r)
        #pragma unroll
        for (int c = 0; c < 16; ++c) acc[r][c] = 0.f;

    for (int ec = 0; ec < 8; ++ec) {
        __syncthreads();
        {
            const int j4  = (t & 127) * 4;
            const int keb = (t >> 7);
            #pragma unroll
            for (int i = 0; i < 16; ++i) {
                const int ke = keb + i * 2;
                const float4 v = *reinterpret_cast<const float4*>(
                    &W_ih[(size_t)(ec * 32 + ke) * HID + j4]);
                *reinterpret_cast<float4*>(&wS[ke][j4]) = v;
            }
        }
        __syncthreads();

        for (int ke = 0; ke < 32; ++ke) {
            float a8[8];
            *(float4*)&a8[0] = *(const float4*)&aT[ec * 32 + ke][rg * 8];
            *(float4*)&a8[4] = *(const float4*)&aT[ec * 32 + ke][rg * 8 + 4];
            float w16[16];
            #pragma unroll
            for (int q = 0; q < 4; ++q)
                *(float4*)&w16[q * 4] =
                    *(const float4*)&wS[ke][cg * 16 + q * 4];
            #pragma unroll
            for (int r = 0; r < 8; ++r)
                #pragma unroll
                for (int c = 0; c < 16; ++c)
                    acc[r][c] = fmaf(a8[r], w16[c], acc[r][c]);
        }
    }

    float bh[16];
    #pragma unroll
    for (int q = 0; q < 4; ++q)
        *(float4*)&bh[q * 4] = *(const float4*)&b_h[cg * 16 + q * 4];
    #pragma unroll
    for (int r = 0; r < 8; ++r) {
        const size_t orow = (size_t)(row0 + rg * 8 + r) * HID + cg * 16;
        #pragma unroll
        for (int q = 0; q < 4; ++q) {
            float4 v;
            v.x = acc[r][q * 4 + 0] + bh[q * 4 + 0];
            v.y = acc[r][q * 4 + 1] + bh[q * 4 + 1];
            v.z = acc[r][q * 4 + 2] + bh[q * 4 + 2];
            v.w = acc[r][q * 4 + 3] + bh[q * 4 + 3];
            *reinterpret_cast<float4*>(&embW[orow + q * 4]) = v;
        }
    }
}

// ---------------------------------------------------------------------------
// Kernel B: sequential RNN, latency-pipelined.
// Block = 2 batch rows, 512 threads = 128 col-groups (4 adjacent cols each)
//   x 4 k-quarters (128 k each). 8 accumulators/thread (4 cols x 2 batches).
// W_hh loads: float4 (16 B/lane, coalesced), ping-pong register pipeline
//   wA/wB of 16 rows each -> next chunk's 16 loads in flight while current
//   chunk computes (compiler emits counted vmcnt). Chunk (cc+1)&7 prefetch
//   at cc=7 warms chunk 0 for the NEXT timestep (weights are ts-invariant).
// k-quarter partials combined via 16 KB LDS pbuf each step.
// NOTE: macro parameter deliberately named WR -- a parameter named `w`
// collides with the .w member token during macro expansion (R2 lesson).
// ---------------------------------------------------------------------------
__global__ __launch_bounds__(512, 2) void rnn_kernel(
    const int* __restrict__ inputs, const float* __restrict__ embW,
    const float* __restrict__ W_hh, float* __restrict__ h_final)
{
    __shared__ __align__(16) float hbuf[2][HID][2];   // [buf][k][g]  8 KB
    __shared__ __align__(16) float pbuf[4][128][8];   // [kq][jg][c*2+g] 16 KB

    const int t  = threadIdx.x;
    const int jg = t & 127;        // column group: cols 4*jg .. 4*jg+3
    const int kq = t >> 7;         // k-quarter:    k in [kq*128, kq*128+128)
    const int b0 = blockIdx.x * 2;

    hbuf[0][t][0] = 0.f;
    hbuf[0][t][1] = 0.f;
    __syncthreads();

    const float* wq = W_hh + (size_t)(kq * 128) * HID + jg * 4;

    float4 wA[16], wB[16];
    #pragma unroll
    for (int i = 0; i < 16; ++i)
        wA[i] = *(const float4*)(wq + (size_t)i * HID);

// compute one 16-k chunk from register buffer `WR`, accumulate 8 accs
#define RNN_CHUNK(WR, cc)                                                     \
    {                                                                         \
        _Pragma("unroll")                                                     \
        for (int i2 = 0; i2 < 8; ++i2) {                                      \
            const float4 h4 =                                                 \
                *(const float4*)&hq[((cc) * 16 + i2 * 2) * 2];                \
            const float4 u0 = WR[i2 * 2];                                     \
            const float4 u1 = WR[i2 * 2 + 1];                                 \
            acc[0] = fmaf(u0.x, h4.x, acc[0]);                                \
            acc[2] = fmaf(u0.y, h4.x, acc[2]);                                \
            acc[4] = fmaf(u0.z, h4.x, acc[4]);                                \
            acc[6] = fmaf(u0.w, h4.x, acc[6]);                                \
            acc[1] = fmaf(u0.x, h4.y, acc[1]);                                \
            acc[3] = fmaf(u0.y, h4.y, acc[3]);                                \
            acc[5] = fmaf(u0.z, h4.y, acc[5]);                                \
            acc[7] = fmaf(u0.w, h4.y, acc[7]);                                \
            acc[0] = fmaf(u1.x, h4.z, acc[0]);                                \
            acc[2] = fmaf(u1.y, h4.z, acc[2]);                                \
            acc[4] = fmaf(u1.z, h4.z, acc[4]);                                \
            acc[6] = fmaf(u1.w, h4.z, acc[6]);                                \
            acc[1] = fmaf(u1.x, h4.w, acc[1]);                                \
            acc[3] = fmaf(u1.y, h4.w, acc[3]);                                \
            acc[5] = fmaf(u1.z, h4.w, acc[5]);                                \
            acc[7] = fmaf(u1.w, h4.w, acc[7]);                                \
        }                                                                     \
    }

    int cur = 0;
    for (int ts = 0; ts < MAXLEN; ++ts) {
        // gather feedforward terms early (consumed after k-loop; latency
        // hidden under ~5k cycles of FMA)
        const int tok0 = inputs[b0 * MAXLEN + ts];
        const int tok1 = inputs[(b0 + 1) * MAXLEN + ts];
        const float e0 = embW[(size_t)tok0 * HID + t];
        const float e1 = embW[(size_t)tok1 * HID + t];

        float acc[8];
        #pragma unroll
        for (int i = 0; i < 8; ++i) acc[i] = 0.f;

        const float* hq = &hbuf[cur][kq * 128][0];

        #pragma unroll
        for (int cc = 0; cc < 8; ++cc) {
            const float* wnext = wq + (size_t)(((cc + 1) & 7) * 16) * HID;
            if ((cc & 1) == 0) {
                #pragma unroll
                for (int i = 0; i < 16; ++i)
                    wB[i] = *(const float4*)(wnext + (size_t)i * HID);
                RNN_CHUNK(wA, cc);
            } else {
                #pragma unroll
                for (int i = 0; i < 16; ++i)
                    wA[i] = *(const float4*)(wnext + (size_t)i * HID);
                RNN_CHUNK(wB, cc);
            }
        }

        // write 8 partials (acc idx = c*2+g), combine across k-quarters
        *(float4*)&pbuf[kq][jg][0] = make_float4(acc[0], acc[1], acc[2], acc[3]);
        *(float4*)&pbuf[kq][jg][4] = make_float4(acc[4], acc[5], acc[6], acc[7]);
        __syncthreads();

        float s0 = e0, s1 = e1;
        #pragma unroll
        for (int q = 0; q < 4; ++q) {
            const float2 p = *(const float2*)&pbuf[q][t >> 2][(t & 3) * 2];
            s0 += p.x;
            s1 += p.y;
        }
        hbuf[cur ^ 1][t][0] = tanhf(s0);
        hbuf[cur ^ 1][t][1] = tanhf(s1);
        __syncthreads();
        cur ^= 1;
    }
#undef RNN_CHUNK

    h_final[(size_t)b0 * HID + t]       = hbuf[cur][t][0];
    h_final[(size_t)(b0 + 1) * HID + t] = hbuf[cur][t][1];
}

// ---------------------------------------------------------------------------
// Kernel C: logits = h_final @ W_out + b_out, sigmoid. Tiny.
// ---------------------------------------------------------------------------
__global__ void head_kernel(const float* __restrict__ h_final,
                            const float* __restrict__ W_out,
                            const float* __restrict__ b_out,
                            float* __restrict__ out)
{
    const int t = threadIdx.x;
    const int b = t >> 1, c = t & 1;
    float acc = b_out[c];
    for (int k = 0; k < HID; ++k)
        acc = fmaf(h_final[(size_t)b * HID + k], W_out[k * NCLASS + c], acc);
    out[t] = 1.f / (1.f + expf(-acc));
}

// ---------------------------------------------------------------------------
extern "C" void kernel_launch(void* const* d_in, const int* in_sizes, int n_in,
                              void* d_out, int out_size, void* d_ws,
                              size_t ws_size, hipStream_t stream)
{
    const int*   inputs = (const int*)  d_in[0];
    const float* emb    = (const float*)d_in[1];
    const float* W_ih   = (const float*)d_in[2];
    const float* W_hh   = (const float*)d_in[3];
    const float* b_h    = (const float*)d_in[4];
    const float* W_out  = (const float*)d_in[5];
    const float* b_out  = (const float*)d_in[6];
    float* out = (float*)d_out;

    float* embW    = (float*)d_ws;                     // 32000*512 f32
    float* h_final = embW + (size_t)VOCAB * HID;       // 128*512 f32

    embw_kernel<<<VOCAB / 64, 256, 0, stream>>>(emb, W_ih, b_h, embW);
    rnn_kernel<<<BATCH / 2, 512, 0, stream>>>(inputs, embW, W_hh, h_final);
    head_kernel<<<1, 256, 0, stream>>>(h_final, W_out, b_out, out);
}

// Round 4
// 7596.907 us; speedup vs baseline: 5.8207x; 5.8207x over previous
//
#include <hip/hip_runtime.h>
#include <math.h>

#define VOCAB  32000
#define EMB    256
#define HID    512
#define MAXLEN 512
#define BATCH  128
#define NCLASS 2

// ---------------------------------------------------------------------------
// Kernel A: embW[v][j] = b_h[j] + sum_e emb[v][e] * W_ih[e][j]
// (unchanged from R0 — ~70 us, not the bottleneck)
// ---------------------------------------------------------------------------
__global__ __launch_bounds__(256, 1) void embw_kernel(
    const float* __restrict__ emb, const float* __restrict__ W_ih,
    const float* __restrict__ b_h, float* __restrict__ embW)
{
    __shared__ __align__(16) float aT[EMB][64];
    __shared__ __align__(16) float wS[32][HID];

    const int t    = threadIdx.x;
    const int row0 = blockIdx.x * 64;

    {
        const int row   = t >> 2;
        const int elane = t & 3;
        for (int i = 0; i < 16; ++i) {
            const int e = elane * 4 + i * 16;
            const float4 v = *reinterpret_cast<const float4*>(
                &emb[(size_t)(row0 + row) * EMB + e]);
            aT[e + 0][row] = v.x;
            aT[e + 1][row] = v.y;
            aT[e + 2][row] = v.z;
            aT[e + 3][row] = v.w;
        }
    }

    const int rg = t >> 5;
    const int cg = t & 31;

    float acc[8][16];
    #pragma unroll
    for (int r = 0; r < 8; ++r)
        #pragma unroll
        for (int c = 0; c < 16; ++c) acc[r][c] = 0.f;

    for (int ec = 0; ec < 8; ++ec) {
        __syncthreads();
        {
            const int j4  = (t & 127) * 4;
            const int keb = (t >> 7);
            #pragma unroll
            for (int i = 0; i < 16; ++i) {
                const int ke = keb + i * 2;
                const float4 v = *reinterpret_cast<const float4*>(
                    &W_ih[(size_t)(ec * 32 + ke) * HID + j4]);
                *reinterpret_cast<float4*>(&wS[ke][j4]) = v;
            }
        }
        __syncthreads();

        for (int ke = 0; ke < 32; ++ke) {
            float a8[8];
            *(float4*)&a8[0] = *(const float4*)&aT[ec * 32 + ke][rg * 8];
            *(float4*)&a8[4] = *(const float4*)&aT[ec * 32 + ke][rg * 8 + 4];
            float w16[16];
            #pragma unroll
            for (int q = 0; q < 4; ++q)
                *(float4*)&w16[q * 4] =
                    *(const float4*)&wS[ke][cg * 16 + q * 4];
            #pragma unroll
            for (int r = 0; r < 8; ++r)
                #pragma unroll
                for (int c = 0; c < 16; ++c)
                    acc[r][c] = fmaf(a8[r], w16[c], acc[r][c]);
        }
    }

    float bh[16];
    #pragma unroll
    for (int q = 0; q < 4; ++q)
        *(float4*)&bh[q * 4] = *(const float4*)&b_h[cg * 16 + q * 4];
    #pragma unroll
    for (int r = 0; r < 8; ++r) {
        const size_t orow = (size_t)(row0 + rg * 8 + r) * HID + cg * 16;
        #pragma unroll
        for (int q = 0; q < 4; ++q) {
            float4 v;
            v.x = acc[r][q * 4 + 0] + bh[q * 4 + 0];
            v.y = acc[r][q * 4 + 1] + bh[q * 4 + 1];
            v.z = acc[r][q * 4 + 2] + bh[q * 4 + 2];
            v.w = acc[r][q * 4 + 3] + bh[q * 4 + 3];
            *reinterpret_cast<float4*>(&embW[orow + q * 4]) = v;
        }
    }
}

// ---------------------------------------------------------------------------
// Kernel B: sequential RNN.
// 64 blocks x 1024 threads (16 waves, 4 waves/SIMD), 2 batch rows/block.
// Thread identity in k-loop: cp = t&255 (columns 2cp, 2cp+1), kq = t>>8
//   (k in [kq*128, kq*128+128)). 4 accumulators (2 cols x 2 rows).
// W_hh: float2 loads, lockstep row-order (R0's proven L2-resident pattern;
//   R2 lesson: NO giant register ping-pong — VGPR cap 128 at 4 waves/SIMD,
//   spill/remat destroyed the pipeline and blew FETCH to 27 GB).
// Chunked k-loop (8 chunks x 16 k): 16 loads grouped -> batched vmcnt,
//   latency hidden by 4 waves/SIMD. h via broadcast ds_read_b128.
// Partials combined via pbuf; combine identity: jj = t&511, g = t>>9.
// embW gather issued at step-top (combine identity) so L3 latency hides
//   under the k-loop.
// ---------------------------------------------------------------------------
__global__ __launch_bounds__(1024, 4) void rnn_kernel(
    const int* __restrict__ inputs, const float* __restrict__ embW,
    const float* __restrict__ W_hh, float* __restrict__ h_final)
{
    __shared__ __align__(16) float hbuf[2][HID][2];    // [buf][k][g]   8 KB
    __shared__ __align__(16) float pbuf[4][256][4];    // [kq][cp][c*2+g] 16 KB

    const int t  = threadIdx.x;
    const int cp = t & 255;       // column pair (k-loop identity)
    const int kq = t >> 8;        // k-quarter
    const int jj = t & 511;       // output column (combine identity)
    const int g  = t >> 9;        // batch row within block (combine identity)
    const int b0 = blockIdx.x * 2;

    ((float*)hbuf)[t] = 0.f;      // zero hbuf[0][*][*] (first 1024 floats)
    __syncthreads();

    const float* wbase = W_hh + (size_t)(kq * 128) * HID + cp * 2;

    int cur = 0;
    for (int ts = 0; ts < MAXLEN; ++ts) {
        // feedforward gather, issued early (used at combine)
        const int tok  = inputs[(b0 + g) * MAXLEN + ts];
        const float ev = embW[(size_t)tok * HID + jj];

        float acc0 = 0.f, acc1 = 0.f, acc2 = 0.f, acc3 = 0.f;
        const float* hq = &hbuf[cur][kq * 128][0];

        #pragma unroll 2
        for (int ck = 0; ck < 8; ++ck) {
            const int k0 = ck * 16;
            float2 wv[16];
            #pragma unroll
            for (int i = 0; i < 16; ++i)
                wv[i] = *(const float2*)(wbase + (size_t)(k0 + i) * HID);
            float4 hv[8];
            #pragma unroll
            for (int i = 0; i < 8; ++i)
                hv[i] = *(const float4*)&hq[(k0 + i * 2) * 2];
            #pragma unroll
            for (int i = 0; i < 8; ++i) {
                const float2 wa = wv[i * 2];
                const float2 wb = wv[i * 2 + 1];
                acc0 = fmaf(wa.x, hv[i].x, acc0);   // col0, row0
                acc1 = fmaf(wa.x, hv[i].y, acc1);   // col0, row1
                acc2 = fmaf(wa.y, hv[i].x, acc2);   // col1, row0
                acc3 = fmaf(wa.y, hv[i].y, acc3);   // col1, row1
                acc0 = fmaf(wb.x, hv[i].z, acc0);
                acc1 = fmaf(wb.x, hv[i].w, acc1);
                acc2 = fmaf(wb.y, hv[i].z, acc2);
                acc3 = fmaf(wb.y, hv[i].w, acc3);
            }
        }

        // acc layout: [c*2+g] = {c0g0, c0g1, c1g0, c1g1}
        *(float4*)&pbuf[kq][cp][0] = make_float4(acc0, acc1, acc2, acc3);
        __syncthreads();

        // combine: thread (jj, g) sums 4 k-quarter partials for its output
        float s = ev;
        #pragma unroll
        for (int q = 0; q < 4; ++q)
            s += pbuf[q][jj >> 1][(jj & 1) * 2 + g];
        hbuf[cur ^ 1][jj][g] = tanhf(s);
        __syncthreads();
        cur ^= 1;
    }

    h_final[(size_t)(b0 + g) * HID + jj] = hbuf[cur][jj][g];
}

// ---------------------------------------------------------------------------
// Kernel C: logits = h_final @ W_out + b_out, sigmoid. Tiny.
// ---------------------------------------------------------------------------
__global__ void head_kernel(const float* __restrict__ h_final,
                            const float* __restrict__ W_out,
                            const float* __restrict__ b_out,
                            float* __restrict__ out)
{
    const int t = threadIdx.x;
    const int b = t >> 1, c = t & 1;
    float acc = b_out[c];
    for (int k = 0; k < HID; ++k)
        acc = fmaf(h_final[(size_t)b * HID + k], W_out[k * NCLASS + c], acc);
    out[t] = 1.f / (1.f + expf(-acc));
}

// ---------------------------------------------------------------------------
extern "C" void kernel_launch(void* const* d_in, const int* in_sizes, int n_in,
                              void* d_out, int out_size, void* d_ws,
                              size_t ws_size, hipStream_t stream)
{
    const int*   inputs = (const int*)  d_in[0];
    const float* emb    = (const float*)d_in[1];
    const float* W_ih   = (const float*)d_in[2];
    const float* W_hh   = (const float*)d_in[3];
    const float* b_h    = (const float*)d_in[4];
    const float* W_out  = (const float*)d_in[5];
    const float* b_out  = (const float*)d_in[6];
    float* out = (float*)d_out;

    float* embW    = (float*)d_ws;                     // 32000*512 f32
    float* h_final = embW + (size_t)VOCAB * HID;       // 128*512 f32

    embw_kernel<<<VOCAB / 64, 256, 0, stream>>>(emb, W_ih, b_h, embW);
    rnn_kernel<<<BATCH / 2, 1024, 0, stream>>>(inputs, embW, W_hh, h_final);
    head_kernel<<<1, 256, 0, stream>>>(h_final, W_out, b_out, out);
}

// Round 5
// 3053.801 us; speedup vs baseline: 14.4800x; 2.4877x over previous
//
#include <hip/hip_runtime.h>
#include <math.h>

#define VOCAB  32000
#define EMB    256
#define HID    512
#define MAXLEN 512
#define BATCH  128
#define NCLASS 2

#define NB_J   8    // column groups of 64 cols
#define NB_B   16   // batch groups of 8 rows
#define ROWS_PB 8   // rows per block
#define COLS_PB 64  // cols per block

// ---------------------------------------------------------------------------
// Kernel A: embW[v][j] = b_h[j] + sum_e emb[v][e] * W_ih[e][j]
// (unchanged — ~70 us)
// ---------------------------------------------------------------------------
__global__ __launch_bounds__(256, 1) void embw_kernel(
    const float* __restrict__ emb, const float* __restrict__ W_ih,
    const float* __restrict__ b_h, float* __restrict__ embW)
{
    __shared__ __align__(16) float aT[EMB][64];
    __shared__ __align__(16) float wS[32][HID];

    const int t    = threadIdx.x;
    const int row0 = blockIdx.x * 64;

    {
        const int row   = t >> 2;
        const int elane = t & 3;
        for (int i = 0; i < 16; ++i) {
            const int e = elane * 4 + i * 16;
            const float4 v = *reinterpret_cast<const float4*>(
                &emb[(size_t)(row0 + row) * EMB + e]);
            aT[e + 0][row] = v.x;
            aT[e + 1][row] = v.y;
            aT[e + 2][row] = v.z;
            aT[e + 3][row] = v.w;
        }
    }

    const int rg = t >> 5;
    const int cg = t & 31;

    float acc[8][16];
    #pragma unroll
    for (int r = 0; r < 8; ++r)
        #pragma unroll
        for (int c = 0; c < 16; ++c) acc[r][c] = 0.f;

    for (int ec = 0; ec < 8; ++ec) {
        __syncthreads();
        {
            const int j4  = (t & 127) * 4;
            const int keb = (t >> 7);
            #pragma unroll
            for (int i = 0; i < 16; ++i) {
                const int ke = keb + i * 2;
                const float4 v = *reinterpret_cast<const float4*>(
                    &W_ih[(size_t)(ec * 32 + ke) * HID + j4]);
                *reinterpret_cast<float4*>(&wS[ke][j4]) = v;
            }
        }
        __syncthreads();

        for (int ke = 0; ke < 32; ++ke) {
            float a8[8];
            *(float4*)&a8[0] = *(const float4*)&aT[ec * 32 + ke][rg * 8];
            *(float4*)&a8[4] = *(const float4*)&aT[ec * 32 + ke][rg * 8 + 4];
            float w16[16];
            #pragma unroll
            for (int q = 0; q < 4; ++q)
                *(float4*)&w16[q * 4] =
                    *(const float4*)&wS[ke][cg * 16 + q * 4];
            #pragma unroll
            for (int r = 0; r < 8; ++r)
                #pragma unroll
                for (int c = 0; c < 16; ++c)
                    acc[r][c] = fmaf(a8[r], w16[c], acc[r][c]);
        }
    }

    float bh[16];
    #pragma unroll
    for (int q = 0; q < 4; ++q)
        *(float4*)&bh[q * 4] = *(const float4*)&b_h[cg * 16 + q * 4];
    #pragma unroll
    for (int r = 0; r < 8; ++r) {
        const size_t orow = (size_t)(row0 + rg * 8 + r) * HID + cg * 16;
        #pragma unroll
        for (int q = 0; q < 4; ++q) {
            float4 v;
            v.x = acc[r][q * 4 + 0] + bh[q * 4 + 0];
            v.y = acc[r][q * 4 + 1] + bh[q * 4 + 1];
            v.z = acc[r][q * 4 + 2] + bh[q * 4 + 2];
            v.w = acc[r][q * 4 + 3] + bh[q * 4 + 3];
            *reinterpret_cast<float4*>(&embW[orow + q * 4]) = v;
        }
    }
}

// ---------------------------------------------------------------------------
// Kernel B: sequential RNN, W-pinned-in-LDS decomposition.
// 128 blocks x 512 threads. Block (bgrp = bid&15, jgrp = bid>>4) owns
//   rows r0..r0+7 (r0 = bgrp*8) x cols j0..j0+63 (j0 = jgrp*64).
// W slice [512 k][64 j] fp32 = 128 KB pinned in LDS before the time loop —
//   ZERO W traffic per step (R3 lesson: 1 MB/step/CU from L2 was the wall).
// Per step: 8 sibling blocks (same bgrp, all jgrps) exchange h through
//   global ping-pong buffers with agent-scope relaxed atomics (cache-
//   bypassing -> correct under XCD L2 non-coherence), then meet at a
//   per-(bgrp,step) 8-block atomic barrier. bgrp = bid%16 => siblings land
//   on one XCD under round-robin placement (perf-only assumption).
// k-loop thread map: lane l = j (64 cols), wave w: kq = w>>1 (k-quarter),
//   rh = w&1 (row half: 4 rows). 4 acc/thread; partials combined via pb.
// ---------------------------------------------------------------------------
__global__ __launch_bounds__(512, 1) void rnn_kernel(
    const int* __restrict__ inputs, const float* __restrict__ embW,
    const float* __restrict__ W_hh, float* hA, float* hB,
    int* bar)
{
    __shared__ __align__(16) float Wl[HID][COLS_PB];        // 128 KB
    __shared__ __align__(16) float hs[HID][ROWS_PB];        // 16 KB
    __shared__ __align__(16) float pb[4][ROWS_PB][COLS_PB]; // 8 KB

    const int t    = threadIdx.x;
    const int w    = t >> 6;          // wave 0..7
    const int l    = t & 63;          // lane 0..63
    const int bid  = blockIdx.x;
    const int bgrp = bid & 15;
    const int jgrp = bid >> 4;
    const int j0   = jgrp * COLS_PB;
    const int r0   = bgrp * ROWS_PB;
    const int kq   = w >> 1;          // k-quarter 0..3
    const int rh   = w & 1;           // row half 0..1

    // ---- stage W slice once (wave w covers k rows w*64 .. w*64+63) ----
    for (int i = 0; i < 64; ++i) {
        const int k = w * 64 + i;
        Wl[k][l] = W_hh[(size_t)k * HID + j0 + l];
    }
    __syncthreads();

    float* hbufs[2] = {hA, hB};

    for (int ts = 0; ts < MAXLEN; ++ts) {
        const float* hc = hbufs[ts & 1];
        float*       hn = hbufs[(ts + 1) & 1];

        // ---- load this bgrp's h rows (agent-scope, cache-bypassing) ----
        // thread (w,l): row r0+w, cols l, l+64, ..., l+448 (wave-coalesced)
        float hv[8];
        #pragma unroll
        for (int q = 0; q < 8; ++q)
            hv[q] = __hip_atomic_load(&hc[(size_t)(r0 + w) * HID + q * 64 + l],
                                      __ATOMIC_RELAXED, __HIP_MEMORY_SCOPE_AGENT);

        // feedforward gather for the combine identity (r=w, j=l)
        const int   tok = inputs[(r0 + w) * MAXLEN + ts];
        const float ev  = embW[(size_t)tok * HID + j0 + l];

        // stage h into LDS as [k][r]
        #pragma unroll
        for (int q = 0; q < 8; ++q)
            hs[q * 64 + l][w] = hv[q];
        __syncthreads();

        // ---- k-loop: thread owns col l, rows rh*4..rh*4+3, k-quarter kq --
        float a0 = 0.f, a1 = 0.f, a2 = 0.f, a3 = 0.f;
        const int kb = kq * 128;
        #pragma unroll 4
        for (int k = kb; k < kb + 128; ++k) {
            const float  wv = Wl[k][l];
            const float4 h4 = *(const float4*)&hs[k][rh * 4];
            a0 = fmaf(wv, h4.x, a0);
            a1 = fmaf(wv, h4.y, a1);
            a2 = fmaf(wv, h4.z, a2);
            a3 = fmaf(wv, h4.w, a3);
        }
        pb[kq][rh * 4 + 0][l] = a0;
        pb[kq][rh * 4 + 1][l] = a1;
        pb[kq][rh * 4 + 2][l] = a2;
        pb[kq][rh * 4 + 3][l] = a3;
        __syncthreads();

        // ---- combine (r=w, j=l), tanh, publish ----
        float s = ev;
        #pragma unroll
        for (int q = 0; q < 4; ++q) s += pb[q][w][l];
        s = tanhf(s);
        __hip_atomic_store(&hn[(size_t)(r0 + w) * HID + j0 + l], s,
                           __ATOMIC_RELAXED, __HIP_MEMORY_SCOPE_AGENT);
        __syncthreads();   // drains vmcnt: all 512 threads' stores complete

        // ---- 8-block barrier for this bgrp at this step ----
        if (t == 0) {
            int* c = &bar[bgrp * MAXLEN + ts];
            __hip_atomic_fetch_add(c, 1, __ATOMIC_ACQ_REL,
                                   __HIP_MEMORY_SCOPE_AGENT);
            while (__hip_atomic_load(c, __ATOMIC_ACQUIRE,
                                     __HIP_MEMORY_SCOPE_AGENT) < NB_J) {
                __builtin_amdgcn_s_sleep(1);
            }
        }
        __syncthreads();
    }
    // final h lives in hbufs[MAXLEN & 1] = hA (MAXLEN even)
}

// ---------------------------------------------------------------------------
// Kernel C: logits = hA @ W_out + b_out, sigmoid. Tiny.
// ---------------------------------------------------------------------------
__global__ void head_kernel(const float* __restrict__ h_final,
                            const float* __restrict__ W_out,
                            const float* __restrict__ b_out,
                            float* __restrict__ out)
{
    const int t = threadIdx.x;
    const int b = t >> 1, c = t & 1;
    float acc = b_out[c];
    for (int k = 0; k < HID; ++k)
        acc = fmaf(h_final[(size_t)b * HID + k], W_out[k * NCLASS + c], acc);
    out[t] = 1.f / (1.f + expf(-acc));
}

// ---------------------------------------------------------------------------
extern "C" void kernel_launch(void* const* d_in, const int* in_sizes, int n_in,
                              void* d_out, int out_size, void* d_ws,
                              size_t ws_size, hipStream_t stream)
{
    const int*   inputs = (const int*)  d_in[0];
    const float* emb    = (const float*)d_in[1];
    const float* W_ih   = (const float*)d_in[2];
    const float* W_hh   = (const float*)d_in[3];
    const float* b_h    = (const float*)d_in[4];
    const float* W_out  = (const float*)d_in[5];
    const float* b_out  = (const float*)d_in[6];
    float* out = (float*)d_out;

    // ws layout: embW 64 MB | hA 256 KB | hB 256 KB | bar 32 KB
    float* embW = (float*)d_ws;
    float* hA   = embW + (size_t)VOCAB * HID;
    float* hB   = hA + (size_t)BATCH * HID;
    int*   bar  = (int*)(hB + (size_t)BATCH * HID);

    // per-launch re-init (graph-capture-safe, deterministic)
    hipMemsetAsync(hA, 0, (size_t)BATCH * HID * sizeof(float), stream);
    hipMemsetAsync(bar, 0, (size_t)NB_B * MAXLEN * sizeof(int), stream);

    embw_kernel<<<VOCAB / 64, 256, 0, stream>>>(emb, W_ih, b_h, embW);
    rnn_kernel<<<NB_B * NB_J, 512, 0, stream>>>(inputs, embW, W_hh,
                                                hA, hB, bar);
    head_kernel<<<1, 256, 0, stream>>>(hA, W_out, b_out, out);
}